// Round 4
// baseline (599.540 us; speedup 1.0000x reference)
//
#include <hip/hip_runtime.h>
#include <math.h>

#define H_IMG 1080
#define W_IMG 1920
#define NPIX (H_IMG * W_IMG)
#define W4 480                                 // W_IMG / 4
#define QUADS (NPIX / 4)                       // 518400
#define RB 2025                                // QUADS / 256, exact
#define NACC 27

// ---- workspace layout (byte offsets) ----
#define OFF_POSE     0                         // 16 f32
#define OFF_MINMAX   64                        // 2 u32
#define OFF_COUNT    128                       // 1 u32 (last-block ticket)
#define OFF_PARTIALS 512                       // NACC * RB f64 = 437400 B
#define OFF_ND       442880                    // NPIX float4 (nx,ny,nz,depth1)
#define WS_NEEDED    ((size_t)OFF_ND + (size_t)NPIX * 16)

__device__ __forceinline__ float clampf(float x, float lo, float hi) {
    return fminf(fmaxf(x, lo), hi);
}

__global__ void k_init(const float* __restrict__ pose_in, float* __restrict__ ws_pose,
                       unsigned int* __restrict__ minmax, unsigned int* __restrict__ counter) {
    int t = threadIdx.x;
    if (t < 16) ws_pose[t] = pose_in[t];
    if (t == 16) { minmax[0] = 0x7F800000u; minmax[1] = 0u; }
    if (t == 17) *counter = 0u;
}

// normals (UNMASKED — invalid mask deferred to k_resid gathers) + depth1 min/max.
// 4 consecutive pixels per thread; writes packed (nx, ny, nz, depth1).
__global__ __launch_bounds__(256)
void k_nm(const float* __restrict__ depth1, const float* __restrict__ Kmat,
          float4* __restrict__ nd, unsigned int* __restrict__ minmax) {
    int tid = threadIdx.x;
    int qid = blockIdx.x * 256 + tid;          // grid exactly RB*256 == QUADS
    float fx = Kmat[0], cx = Kmat[2], fy = Kmat[4], cy = Kmat[5];
    float ifx = 1.f / fx, ify = 1.f / fy;
    int j = qid / W4;
    int i0 = (qid - j * W4) * 4;
    int r0 = j > 0 ? j - 1 : 0;
    int r2 = j < H_IMG - 1 ? j + 1 : H_IMG - 1;
    int il = i0 > 0 ? i0 - 1 : 0;
    int ir = i0 + 4 < W_IMG ? i0 + 4 : W_IMG - 1;
    const float* rp[3] = { depth1 + (size_t)r0 * W_IMG,
                           depth1 + (size_t)j  * W_IMG,
                           depth1 + (size_t)r2 * W_IMG };
    float d[3][6];
#pragma unroll
    for (int r = 0; r < 3; r++) {
        float4 m = *reinterpret_cast<const float4*>(rp[r] + i0);
        d[r][0] = rp[r][il]; d[r][1] = m.x; d[r][2] = m.y; d[r][3] = m.z; d[r][4] = m.w; d[r][5] = rp[r][ir];
    }
    float rowc[3] = { ((float)r0 - cy) * ify, ((float)j - cy) * ify, ((float)r2 - cy) * ify };
    float colc[6];
#pragma unroll
    for (int c = 0; c < 6; c++) {
        int col = i0 - 1 + c; col = col < 0 ? 0 : (col > W_IMG - 1 ? W_IMG - 1 : col);
        colc[c] = ((float)col - cx) * ifx;
    }
    float vx[3][6], vy[3][6];
#pragma unroll
    for (int r = 0; r < 3; r++)
#pragma unroll
        for (int c = 0; c < 6; c++) { vx[r][c] = colc[c] * d[r][c]; vy[r][c] = rowc[r] * d[r][c]; }
    float4 out[4];
#pragma unroll
    for (int p = 0; p < 4; p++) {
        int a = p, b = p + 1, e = p + 2;
        float dxx = -vx[0][a] + vx[0][e] - 2.f * vx[1][a] + 2.f * vx[1][e] - vx[2][a] + vx[2][e];
        float dxy = -vy[0][a] + vy[0][e] - 2.f * vy[1][a] + 2.f * vy[1][e] - vy[2][a] + vy[2][e];
        float dxz = -d[0][a] + d[0][e] - 2.f * d[1][a] + 2.f * d[1][e] - d[2][a] + d[2][e];
        float dyx = -vx[0][a] - 2.f * vx[0][b] - vx[0][e] + vx[2][a] + 2.f * vx[2][b] + vx[2][e];
        float dyy = -vy[0][a] - 2.f * vy[0][b] - vy[0][e] + vy[2][a] + 2.f * vy[2][b] + vy[2][e];
        float dyz = -d[0][a] - 2.f * d[0][b] - d[0][e] + d[2][a] + 2.f * d[2][b] + d[2][e];
        float nx = dxy * dyz - dxz * dyy;
        float ny = dxz * dyx - dxx * dyz;
        float nz = dxx * dyy - dxy * dyx;
        float inv = 1.f / (sqrtf(nx * nx + ny * ny + nz * nz) + 1e-8f);
        out[p].x = nx * inv; out[p].y = ny * inv; out[p].z = nz * inv; out[p].w = d[1][b];
    }
    float4* dst = nd + (size_t)j * W_IMG + i0;
#pragma unroll
    for (int p = 0; p < 4; p++) dst[p] = out[p];

    // block min/max of the 4 center depths -> 2 atomics/block
    float mn = fminf(fminf(d[1][1], d[1][2]), fminf(d[1][3], d[1][4]));
    float mx = fmaxf(fmaxf(d[1][1], d[1][2]), fmaxf(d[1][3], d[1][4]));
    for (int off = 32; off > 0; off >>= 1) {
        mn = fminf(mn, __shfl_down(mn, off));
        mx = fmaxf(mx, __shfl_down(mx, off));
    }
    __shared__ float smn[4], smx[4];
    int lane = tid & 63, wid = tid >> 6;
    if (lane == 0) { smn[wid] = mn; smx[wid] = mx; }
    __syncthreads();
    if (tid == 0) {
        for (int w = 1; w < 4; w++) { mn = fminf(mn, smn[w]); mx = fmaxf(mx, smx[w]); }
        atomicMin(&minmax[0], __float_as_uint(mn));  // positive floats: bit order == value order
        atomicMax(&minmax[1], __float_as_uint(mx));
    }
}

// residual+Jacobian accumulation with fused last-block reduce + 6x6 GN solve.
__global__ __launch_bounds__(256)
void k_resid(const float4* __restrict__ depth0q, const float* __restrict__ Kmat,
             const float4* __restrict__ nd, const unsigned int* __restrict__ minmax,
             float* __restrict__ pose, double* __restrict__ partials,
             unsigned int* __restrict__ counter, float* __restrict__ pose_out) {
    float fx = Kmat[0], cx = Kmat[2], fy = Kmat[4], cy = Kmat[5];
    float ifx = 1.f / fx, ify = 1.f / fy;
    float R00 = pose[0], R01 = pose[1], R02 = pose[2],  t0 = pose[3];
    float R10 = pose[4], R11 = pose[5], R12 = pose[6],  t1 = pose[7];
    float R20 = pose[8], R21 = pose[9], R22 = pose[10], t2 = pose[11];
    float dmin = __uint_as_float(minmax[0]);
    float dmax = __uint_as_float(minmax[1]);

    float acc[NACC];
#pragma unroll
    for (int k = 0; k < NACC; k++) acc[k] = 0.f;

    int tid = threadIdx.x;
    int qid = blockIdx.x * 256 + tid;          // grid exactly RB*256 == QUADS
    int j = qid / W4;
    int i0 = (qid - j * W4) * 4;
    float jf = (float)j;
    float4 d4 = depth0q[qid];
    float d0s[4] = {d4.x, d4.y, d4.z, d4.w};

#pragma unroll
    for (int pp = 0; pp < 2; pp++) {
        float px[2], py[2], pz[2], wx[2], wy[2];
        int x0[2], x1[2], y0[2], y1[2];
        bool inview[2];
        float d0v[2];
#pragma unroll
        for (int q = 0; q < 2; q++) {
            int p = pp * 2 + q;
            float d0 = d0s[p];
            d0v[q] = d0;
            float v0x = ((float)(i0 + p) - cx) * ifx * d0;
            float v0y = (jf - cy) * ify * d0;
            float X = R00 * v0x + R01 * v0y + R02 * d0 + t0;
            float Y = R10 * v0x + R11 * v0y + R12 * d0 + t1;
            float Z = R20 * v0x + R21 * v0y + R22 * d0 + t2;
            float u, v; bool iv;
            if (Z > 1e-6f) {
                float rz = 1.f / Z;
                u = X * rz * fx + cx;
                v = Y * rz * fy + cy;
                iv = (u > 0.f) && (u < (float)(W_IMG - 1)) && (v > 0.f) && (v < (float)(H_IMG - 1));
            } else { u = 0.f; v = 0.f; iv = false; }
            float uc = clampf(u, 0.f, (float)(W_IMG - 1));
            float vc = clampf(v, 0.f, (float)(H_IMG - 1));
            float x0f = floorf(uc), y0f = floorf(vc);
            x0[q] = (int)x0f; y0[q] = (int)y0f;
            x1[q] = min(x0[q] + 1, W_IMG - 1);
            y1[q] = min(y0[q] + 1, H_IMG - 1);
            wx[q] = uc - x0f; wy[q] = vc - y0f;
            px[q] = X; py[q] = Y; pz[q] = Z; inview[q] = iv;
        }
        float4 c00[2], c01[2], c10[2], c11[2];
#pragma unroll
        for (int q = 0; q < 2; q++) {
            int i00 = y0[q] * W_IMG + x0[q], i01 = y0[q] * W_IMG + x1[q];
            int i10 = y1[q] * W_IMG + x0[q], i11 = y1[q] * W_IMG + x1[q];
            c00[q] = nd[i00]; c01[q] = nd[i01]; c10[q] = nd[i10]; c11[q] = nd[i11];
        }
        // deferred _compute_normal invalid mask: zero corner normal at global depth min/max
#pragma unroll
        for (int q = 0; q < 2; q++) {
            float4* cs[4] = {&c00[q], &c01[q], &c10[q], &c11[q]};
#pragma unroll
            for (int m = 0; m < 4; m++) {
                bool inv = (cs[m]->w <= dmin) || (cs[m]->w >= dmax);
                if (inv) { cs[m]->x = 0.f; cs[m]->y = 0.f; cs[m]->z = 0.f; }
            }
        }
#pragma unroll
        for (int q = 0; q < 2; q++) {
            float w1x = 1.f - wx[q], w1y = 1.f - wy[q];
            float d00 = c00[q].w, d01 = c01[q].w, d10 = c10[q].w, d11 = c11[q].w;
            float cX0 = ((float)x0[q] - cx) * ifx, cX1 = ((float)x1[q] - cx) * ifx;
            float cY0 = ((float)y0[q] - cy) * ify, cY1 = ((float)y1[q] - cy) * ify;
            float rvx = (cX0 * d00 * w1x + cX1 * d01 * wx[q]) * w1y + (cX0 * d10 * w1x + cX1 * d11 * wx[q]) * wy[q];
            float rvy = (cY0 * d00 * w1x + cY0 * d01 * wx[q]) * w1y + (cY1 * d10 * w1x + cY1 * d11 * wx[q]) * wy[q];
            float rvz = (d00 * w1x + d01 * wx[q]) * w1y + (d10 * w1x + d11 * wx[q]) * wy[q];
            float rnx = (c00[q].x * w1x + c01[q].x * wx[q]) * w1y + (c10[q].x * w1x + c11[q].x * wx[q]) * wy[q];
            float rny = (c00[q].y * w1x + c01[q].y * wx[q]) * w1y + (c10[q].y * w1x + c11[q].y * wx[q]) * wy[q];
            float rnz = (c00[q].z * w1x + c01[q].z * wx[q]) * w1y + (c10[q].z * w1x + c11[q].z * wx[q]) * wy[q];
            bool mask1 = rvz > 0.f;
            float ddx = px[q] - rvx, ddy = py[q] - rvy, ddz = pz[q] - rvz;
            bool occ = (!inview[q]) || (sqrtf(ddx * ddx + ddy * ddy + ddz * ddz) > 0.1f);
            bool bad = occ || !(d0v[q] > 0.f) || (!mask1);
            if (!bad) {
                float res = rnx * ddx + rny * ddy + rnz * ddz;
                float jv[6];
                jv[0] = -(py[q] * rnz - pz[q] * rny);
                jv[1] = -(pz[q] * rnx - px[q] * rnz);
                jv[2] = -(px[q] * rny - py[q] * rnx);
                jv[3] = -rnx; jv[4] = -rny; jv[5] = -rnz;
                int k = 0;
#pragma unroll
                for (int a = 0; a < 6; a++)
#pragma unroll
                    for (int b = a; b < 6; b++) { acc[k] += jv[a] * jv[b]; k++; }
#pragma unroll
                for (int a = 0; a < 6; a++) acc[21 + a] += jv[a] * res;
            }
        }
    }

    // ---- block reduction: 2x shfl_xor pre-reduce (4 lanes) -> LDS [27][64] ----
    __shared__ float red[NACC][64];
    __shared__ float part2[NACC][8];
    __shared__ int sAmLast;
#pragma unroll
    for (int k = 0; k < NACC; k++) {
        float v = acc[k];
        v += __shfl_xor(v, 1);
        v += __shfl_xor(v, 2);
        if ((tid & 3) == 0) red[k][tid >> 2] = v;
    }
    __syncthreads();
    if (tid < NACC * 8) {
        int k = tid >> 3, seg = tid & 7;
        const float4* row = reinterpret_cast<const float4*>(&red[k][seg * 8]);
        float4 a = row[0], b = row[1];
        part2[k][seg] = (a.x + a.y + a.z + a.w) + (b.x + b.y + b.z + b.w);
    }
    __syncthreads();
    if (tid < NACC) {
        double s = 0.0;
#pragma unroll
        for (int m = 0; m < 8; m++) s += (double)part2[tid][m];
        partials[(size_t)tid * RB + blockIdx.x] = s;
    }
    __syncthreads();

    // ---- last-block-done: reduce partials + GN solve ----
    if (tid == 0) {
        __threadfence();
        unsigned int old = atomicAdd(counter, 1u);
        sAmLast = (old == (unsigned int)(gridDim.x - 1)) ? 1 : 0;
    }
    __syncthreads();
    if (!sAmLast) return;
    __threadfence();

    __shared__ double sred[NACC][8];
    __shared__ double ssum[NACC];
    __shared__ double sM[6][7];
    if (tid < NACC * 8) {
        int k = tid >> 3, seg = tid & 7;
        double s = 0.0;
        for (int i = seg; i < RB; i += 8) s += partials[(size_t)k * RB + i];
        sred[k][seg] = s;
    }
    __syncthreads();
    if (tid < NACC) {
        double s = 0.0;
#pragma unroll
        for (int m = 0; m < 8; m++) s += sred[tid][m];
        ssum[tid] = s;
    }
    __syncthreads();
    if (tid == 0) {
        int k = 0;
        for (int a = 0; a < 6; a++)
            for (int c = a; c < 6; c++) {
                double s = ssum[k++];
                sM[a][c] = s; sM[c][a] = s;
            }
        double tr = sM[0][0] + sM[1][1] + sM[2][2] + sM[3][3] + sM[4][4] + sM[5][5];
        for (int a = 0; a < 6; a++) sM[a][a] += tr * 0.001;
        for (int a = 0; a < 6; a++) sM[a][6] = ssum[21 + a];
        // Gauss-Jordan with partial pivoting (working set in LDS)
        for (int c = 0; c < 6; c++) {
            int piv = c;
            double best = fabs(sM[c][c]);
            for (int r = c + 1; r < 6; r++) {
                double v = fabs(sM[r][c]);
                if (v > best) { best = v; piv = r; }
            }
            if (piv != c)
                for (int q = c; q < 7; q++) { double t = sM[c][q]; sM[c][q] = sM[piv][q]; sM[piv][q] = t; }
            double pv = sM[c][c];
            for (int r = 0; r < 6; r++) {
                if (r == c) continue;
                double f = sM[r][c] / pv;
                for (int q = c; q < 7; q++) sM[r][q] -= f * sM[c][q];
            }
        }
        double xi0 = sM[0][6] / sM[0][0], xi1 = sM[1][6] / sM[1][1], xi2 = sM[2][6] / sM[2][2];
        double xi3 = sM[3][6] / sM[3][3], xi4 = sM[4][6] / sM[4][4], xi5 = sM[5][6] / sM[5][5];
        // exp_so3(xi[0:3])
        double th = sqrt(xi0 * xi0 + xi1 * xi1 + xi2 * xi2);
        double dR[3][3] = {{1, 0, 0}, {0, 1, 0}, {0, 0, 1}};
        if (th > 1e-10) {
            double sA = sin(th) / th;
            double sB = (1.0 - cos(th)) / (th * th);
            double wh[3][3] = {{0, -xi2, xi1}, {xi2, 0, -xi0}, {-xi1, xi0, 0}};
#pragma unroll
            for (int r = 0; r < 3; r++)
#pragma unroll
                for (int cc = 0; cc < 3; cc++) {
                    double w2 = 0;
#pragma unroll
                    for (int m = 0; m < 3; m++) w2 += wh[r][m] * wh[m][cc];
                    dR[r][cc] = (r == cc ? 1.0 : 0.0) + sA * wh[r][cc] + sB * w2;
                }
        }
        double R[3][3], t[3];
#pragma unroll
        for (int r = 0; r < 3; r++) {
#pragma unroll
            for (int cc = 0; cc < 3; cc++) R[r][cc] = pose[r * 4 + cc];
            t[r] = pose[r * 4 + 3];
        }
        double xt[3] = {xi3, xi4, xi5};
#pragma unroll
        for (int r = 0; r < 3; r++) {
#pragma unroll
            for (int cc = 0; cc < 3; cc++) {
                double s = 0;
#pragma unroll
                for (int m = 0; m < 3; m++) s += dR[r][m] * R[m][cc];
                pose[r * 4 + cc] = (float)s;
            }
            pose[r * 4 + 3] = (float)(dR[r][0] * t[0] + dR[r][1] * t[1] + dR[r][2] * t[2] + xt[r]);
        }
        *counter = 0u;                         // re-arm ticket for next dispatch
        for (int q = 0; q < 16; q++) pose_out[q] = pose[q];
    }
}

extern "C" void kernel_launch(void* const* d_in, const int* in_sizes, int n_in,
                              void* d_out, int out_size, void* d_ws, size_t ws_size,
                              hipStream_t stream) {
    const float* pose_in = (const float*)d_in[0];
    const float* depth0 = (const float*)d_in[1];
    const float* depth1 = (const float*)d_in[2];
    const float* K = (const float*)d_in[3];
    float* out = (float*)d_out;
    char* ws = (char*)d_ws;
    float* ws_pose = (float*)(ws + OFF_POSE);
    unsigned int* minmax = (unsigned int*)(ws + OFF_MINMAX);
    unsigned int* counter = (unsigned int*)(ws + OFF_COUNT);
    double* partials = (double*)(ws + OFF_PARTIALS);
    float4* nd = (float4*)(ws + OFF_ND);

    k_init<<<1, 64, 0, stream>>>(pose_in, ws_pose, minmax, counter);
    k_nm<<<RB, 256, 0, stream>>>(depth1, K, nd, minmax);
    for (int it = 0; it < 3; ++it)
        k_resid<<<RB, 256, 0, stream>>>((const float4*)depth0, K, nd, minmax,
                                        ws_pose, partials, counter, out);
}

// Round 5
// 335.755 us; speedup vs baseline: 1.7856x; 1.7856x over previous
//
#include <hip/hip_runtime.h>
#include <math.h>

#define H_IMG 1080
#define W_IMG 1920
#define NPIX (H_IMG * W_IMG)
#define W4 480                                 // W_IMG / 4
#define QUADS (NPIX / 4)                       // 518400
#define RB 2025                                // QUADS / 256, exact
#define NACC 27

// ---- workspace layout (byte offsets) ----
#define OFF_POSE     0                         // 16 f32
#define OFF_MINMAX   64                        // 2 u32
#define OFF_PARTIALS 512                       // NACC * RB f32 = 218700 B
#define OFF_ND16     219648                    // NPIX f16x4 (nx,ny,nz,d) = 16.6 MB (+8B slack after)

typedef _Float16 h4 __attribute__((ext_vector_type(4)));

__device__ __forceinline__ float clampf(float x, float lo, float hi) {
    return fminf(fmaxf(x, lo), hi);
}

__global__ void k_init(const float* __restrict__ pose_in, float* __restrict__ ws_pose,
                       unsigned int* __restrict__ minmax) {
    int t = threadIdx.x;
    if (t < 16) ws_pose[t] = pose_in[t];
    if (t == 16) { minmax[0] = 0x7F800000u; minmax[1] = 0u; }
}

__global__ void k_minmax(const float4* __restrict__ dq, unsigned int* __restrict__ minmax) {
    int tid = blockIdx.x * blockDim.x + threadIdx.x;
    int stride = gridDim.x * blockDim.x;
    float mn = INFINITY, mx = -INFINITY;
    for (int i = tid; i < QUADS; i += stride) {
        float4 v = dq[i];
        mn = fminf(mn, fminf(fminf(v.x, v.y), fminf(v.z, v.w)));
        mx = fmaxf(mx, fmaxf(fmaxf(v.x, v.y), fmaxf(v.z, v.w)));
    }
    for (int off = 32; off > 0; off >>= 1) {
        mn = fminf(mn, __shfl_down(mn, off));
        mx = fmaxf(mx, __shfl_down(mx, off));
    }
    __shared__ float smn[4], smx[4];
    int lane = threadIdx.x & 63, wid = threadIdx.x >> 6;
    if (lane == 0) { smn[wid] = mn; smx[wid] = mx; }
    __syncthreads();
    if (threadIdx.x == 0) {
        for (int w = 1; w < 4; w++) { mn = fminf(mn, smn[w]); mx = fmaxf(mx, smx[w]); }
        atomicMin(&minmax[0], __float_as_uint(mn));  // positive floats: bit order == value order
        atomicMax(&minmax[1], __float_as_uint(mx));
    }
}

// masked normals + depth packed to f16x4 (8 B/px). 4 consecutive pixels per thread.
__global__ __launch_bounds__(256)
void k_nm(const float* __restrict__ depth1, const float* __restrict__ Kmat,
          const unsigned int* __restrict__ minmax, h4* __restrict__ nd16) {
    int tid = threadIdx.x;
    int qid = blockIdx.x * 256 + tid;          // grid exactly RB*256 == QUADS
    float fx = Kmat[0], cx = Kmat[2], fy = Kmat[4], cy = Kmat[5];
    float ifx = 1.f / fx, ify = 1.f / fy;
    float dmin = __uint_as_float(minmax[0]), dmax = __uint_as_float(minmax[1]);
    int j = qid / W4;
    int i0 = (qid - j * W4) * 4;
    int r0 = j > 0 ? j - 1 : 0;
    int r2 = j < H_IMG - 1 ? j + 1 : H_IMG - 1;
    int il = i0 > 0 ? i0 - 1 : 0;
    int ir = i0 + 4 < W_IMG ? i0 + 4 : W_IMG - 1;
    const float* rp[3] = { depth1 + (size_t)r0 * W_IMG,
                           depth1 + (size_t)j  * W_IMG,
                           depth1 + (size_t)r2 * W_IMG };
    float d[3][6];
#pragma unroll
    for (int r = 0; r < 3; r++) {
        float4 m = *reinterpret_cast<const float4*>(rp[r] + i0);
        d[r][0] = rp[r][il]; d[r][1] = m.x; d[r][2] = m.y; d[r][3] = m.z; d[r][4] = m.w; d[r][5] = rp[r][ir];
    }
    float rowc[3] = { ((float)r0 - cy) * ify, ((float)j - cy) * ify, ((float)r2 - cy) * ify };
    float colc[6];
#pragma unroll
    for (int c = 0; c < 6; c++) {
        int col = i0 - 1 + c; col = col < 0 ? 0 : (col > W_IMG - 1 ? W_IMG - 1 : col);
        colc[c] = ((float)col - cx) * ifx;
    }
    float vx[3][6], vy[3][6];
#pragma unroll
    for (int r = 0; r < 3; r++)
#pragma unroll
        for (int c = 0; c < 6; c++) { vx[r][c] = colc[c] * d[r][c]; vy[r][c] = rowc[r] * d[r][c]; }
    h4 out[4];
#pragma unroll
    for (int p = 0; p < 4; p++) {
        int a = p, b = p + 1, e = p + 2;
        float dxx = -vx[0][a] + vx[0][e] - 2.f * vx[1][a] + 2.f * vx[1][e] - vx[2][a] + vx[2][e];
        float dxy = -vy[0][a] + vy[0][e] - 2.f * vy[1][a] + 2.f * vy[1][e] - vy[2][a] + vy[2][e];
        float dxz = -d[0][a] + d[0][e] - 2.f * d[1][a] + 2.f * d[1][e] - d[2][a] + d[2][e];
        float dyx = -vx[0][a] - 2.f * vx[0][b] - vx[0][e] + vx[2][a] + 2.f * vx[2][b] + vx[2][e];
        float dyy = -vy[0][a] - 2.f * vy[0][b] - vy[0][e] + vy[2][a] + 2.f * vy[2][b] + vy[2][e];
        float dyz = -d[0][a] - 2.f * d[0][b] - d[0][e] + d[2][a] + 2.f * d[2][b] + d[2][e];
        float nx = dxy * dyz - dxz * dyy;
        float ny = dxz * dyx - dxx * dyz;
        float nz = dxx * dyy - dxy * dyx;
        float inv = 1.f / (sqrtf(nx * nx + ny * ny + nz * nz) + 1e-8f);
        float dc = d[1][b];
        bool invalid = (dc <= dmin) || (dc >= dmax);   // exact f32 compare pre-pack
        float s = invalid ? 0.f : inv;
        out[p][0] = (_Float16)(nx * s);
        out[p][1] = (_Float16)(ny * s);
        out[p][2] = (_Float16)(nz * s);
        out[p][3] = (_Float16)dc;
    }
    h4* dst = nd16 + (size_t)j * W_IMG + i0;
#pragma unroll
    for (int p = 0; p < 4; p++) dst[p] = out[p];
}

// residual + Jacobian accumulation; f32 per-block partials.
__global__ __launch_bounds__(256)
void k_resid(const float4* __restrict__ depth0q, const float* __restrict__ Kmat,
             const h4* __restrict__ nd16, const float* __restrict__ pose,
             float* __restrict__ partials) {
    float fx = Kmat[0], cx = Kmat[2], fy = Kmat[4], cy = Kmat[5];
    float ifx = 1.f / fx, ify = 1.f / fy;
    float R00 = pose[0], R01 = pose[1], R02 = pose[2],  t0 = pose[3];
    float R10 = pose[4], R11 = pose[5], R12 = pose[6],  t1 = pose[7];
    float R20 = pose[8], R21 = pose[9], R22 = pose[10], t2 = pose[11];

    float acc[NACC];
#pragma unroll
    for (int k = 0; k < NACC; k++) acc[k] = 0.f;

    int tid = threadIdx.x;
    int qid = blockIdx.x * 256 + tid;          // grid exactly RB*256 == QUADS
    int j = qid / W4;
    int i0 = (qid - j * W4) * 4;
    float jf = (float)j;
    float4 d4 = depth0q[qid];
    float d0s[4] = {d4.x, d4.y, d4.z, d4.w};

#pragma unroll
    for (int pp = 0; pp < 2; pp++) {
        float px[2], py[2], pz[2], wx[2], wy[2];
        int x0[2], y0[2];
        bool inview[2];
        float d0v[2];
#pragma unroll
        for (int q = 0; q < 2; q++) {
            int p = pp * 2 + q;
            float d0 = d0s[p];
            d0v[q] = d0;
            float v0x = ((float)(i0 + p) - cx) * ifx * d0;
            float v0y = (jf - cy) * ify * d0;
            float X = R00 * v0x + R01 * v0y + R02 * d0 + t0;
            float Y = R10 * v0x + R11 * v0y + R12 * d0 + t1;
            float Z = R20 * v0x + R21 * v0y + R22 * d0 + t2;
            float u, v; bool iv;
            if (Z > 1e-6f) {
                float rz = 1.f / Z;
                u = X * rz * fx + cx;
                v = Y * rz * fy + cy;
                iv = (u > 0.f) && (u < (float)(W_IMG - 1)) && (v > 0.f) && (v < (float)(H_IMG - 1));
            } else { u = 0.f; v = 0.f; iv = false; }
            float uc = clampf(u, 0.f, (float)(W_IMG - 1));
            float vc = clampf(v, 0.f, (float)(H_IMG - 1));
            float x0f = floorf(uc), y0f = floorf(vc);
            x0[q] = (int)x0f; y0[q] = (int)y0f;
            wx[q] = uc - x0f; wy[q] = vc - y0f;
            px[q] = X; py[q] = Y; pz[q] = Z; inview[q] = iv;
        }
        // 4 gathers of 8 B per pixel; x-corners adjacent (x1==x0+1 whenever inview).
        h4 a0[2], a1[2], b0[2], b1[2];
#pragma unroll
        for (int q = 0; q < 2; q++) {
            int y1 = min(y0[q] + 1, H_IMG - 1);
            int base0 = y0[q] * W_IMG + x0[q];
            int base1 = y1 * W_IMG + x0[q];
            a0[q] = nd16[base0]; a1[q] = nd16[base0 + 1];
            b0[q] = nd16[base1]; b1[q] = nd16[base1 + 1];
        }
#pragma unroll
        for (int q = 0; q < 2; q++) {
            float w1x = 1.f - wx[q], w1y = 1.f - wy[q];
            float d00 = (float)a0[q][3], d01 = (float)a1[q][3];
            float d10 = (float)b0[q][3], d11 = (float)b1[q][3];
            float cX0 = ((float)x0[q] - cx) * ifx, cX1 = ((float)(x0[q] + 1) - cx) * ifx;
            int y1 = min(y0[q] + 1, H_IMG - 1);
            float cY0 = ((float)y0[q] - cy) * ify, cY1 = ((float)y1 - cy) * ify;
            float rvx = (cX0 * d00 * w1x + cX1 * d01 * wx[q]) * w1y + (cX0 * d10 * w1x + cX1 * d11 * wx[q]) * wy[q];
            float rvy = (cY0 * d00 * w1x + cY0 * d01 * wx[q]) * w1y + (cY1 * d10 * w1x + cY1 * d11 * wx[q]) * wy[q];
            float rvz = (d00 * w1x + d01 * wx[q]) * w1y + (d10 * w1x + d11 * wx[q]) * wy[q];
            float rnx = ((float)a0[q][0] * w1x + (float)a1[q][0] * wx[q]) * w1y
                      + ((float)b0[q][0] * w1x + (float)b1[q][0] * wx[q]) * wy[q];
            float rny = ((float)a0[q][1] * w1x + (float)a1[q][1] * wx[q]) * w1y
                      + ((float)b0[q][1] * w1x + (float)b1[q][1] * wx[q]) * wy[q];
            float rnz = ((float)a0[q][2] * w1x + (float)a1[q][2] * wx[q]) * w1y
                      + ((float)b0[q][2] * w1x + (float)b1[q][2] * wx[q]) * wy[q];
            bool mask1 = rvz > 0.f;
            float ddx = px[q] - rvx, ddy = py[q] - rvy, ddz = pz[q] - rvz;
            bool occ = (!inview[q]) || (sqrtf(ddx * ddx + ddy * ddy + ddz * ddz) > 0.1f);
            bool bad = occ || !(d0v[q] > 0.f) || (!mask1);
            if (!bad) {
                float res = rnx * ddx + rny * ddy + rnz * ddz;
                float jv[6];
                jv[0] = -(py[q] * rnz - pz[q] * rny);
                jv[1] = -(pz[q] * rnx - px[q] * rnz);
                jv[2] = -(px[q] * rny - py[q] * rnx);
                jv[3] = -rnx; jv[4] = -rny; jv[5] = -rnz;
                int k = 0;
#pragma unroll
                for (int a = 0; a < 6; a++)
#pragma unroll
                    for (int b = a; b < 6; b++) { acc[k] += jv[a] * jv[b]; k++; }
#pragma unroll
                for (int a = 0; a < 6; a++) acc[21 + a] += jv[a] * res;
            }
        }
    }

    // block reduction: 2x shfl_xor pre-reduce (4 lanes) -> LDS [27][64] -> [27][8] -> f32 partial
    __shared__ float red[NACC][64];
    __shared__ float part2[NACC][8];
#pragma unroll
    for (int k = 0; k < NACC; k++) {
        float v = acc[k];
        v += __shfl_xor(v, 1);
        v += __shfl_xor(v, 2);
        if ((tid & 3) == 0) red[k][tid >> 2] = v;
    }
    __syncthreads();
    if (tid < NACC * 8) {
        int k = tid >> 3, seg = tid & 7;
        const float4* row = reinterpret_cast<const float4*>(&red[k][seg * 8]);
        float4 a = row[0], b = row[1];
        part2[k][seg] = (a.x + a.y + a.z + a.w) + (b.x + b.y + b.z + b.w);
    }
    __syncthreads();
    if (tid < NACC) {
        float s = 0.f;
#pragma unroll
        for (int m = 0; m < 8; m++) s += part2[tid][m];
        partials[(size_t)tid * RB + blockIdx.x] = s;
    }
}

// single block: reduce f32 partials in f64, 6x6 GN solve, update pose, write out.
__global__ __launch_bounds__(256)
void k_finish(const float* __restrict__ partials, float* __restrict__ pose,
              float* __restrict__ pose_out) {
    __shared__ double sred[NACC][8];
    __shared__ double ssum[NACC];
    __shared__ double sM[6][7];
    int tid = threadIdx.x;
    if (tid < NACC * 8) {
        int k = tid >> 3, seg = tid & 7;
        double s = 0.0;
        for (int i = seg; i < RB; i += 8) s += (double)partials[(size_t)k * RB + i];
        sred[k][seg] = s;
    }
    __syncthreads();
    if (tid < NACC) {
        double s = 0.0;
#pragma unroll
        for (int m = 0; m < 8; m++) s += sred[tid][m];
        ssum[tid] = s;
    }
    __syncthreads();
    if (tid == 0) {
        int k = 0;
        for (int a = 0; a < 6; a++)
            for (int c = a; c < 6; c++) {
                double s = ssum[k++];
                sM[a][c] = s; sM[c][a] = s;
            }
        double tr = sM[0][0] + sM[1][1] + sM[2][2] + sM[3][3] + sM[4][4] + sM[5][5];
        for (int a = 0; a < 6; a++) sM[a][a] += tr * 0.001;
        for (int a = 0; a < 6; a++) sM[a][6] = ssum[21 + a];
        for (int c = 0; c < 6; c++) {
            int piv = c;
            double best = fabs(sM[c][c]);
            for (int r = c + 1; r < 6; r++) {
                double v = fabs(sM[r][c]);
                if (v > best) { best = v; piv = r; }
            }
            if (piv != c)
                for (int q = c; q < 7; q++) { double t = sM[c][q]; sM[c][q] = sM[piv][q]; sM[piv][q] = t; }
            double pv = sM[c][c];
            for (int r = 0; r < 6; r++) {
                if (r == c) continue;
                double f = sM[r][c] / pv;
                for (int q = c; q < 7; q++) sM[r][q] -= f * sM[c][q];
            }
        }
        double xi0 = sM[0][6] / sM[0][0], xi1 = sM[1][6] / sM[1][1], xi2 = sM[2][6] / sM[2][2];
        double xi3 = sM[3][6] / sM[3][3], xi4 = sM[4][6] / sM[4][4], xi5 = sM[5][6] / sM[5][5];
        double th = sqrt(xi0 * xi0 + xi1 * xi1 + xi2 * xi2);
        double dR[3][3] = {{1, 0, 0}, {0, 1, 0}, {0, 0, 1}};
        if (th > 1e-10) {
            double sA = sin(th) / th;
            double sB = (1.0 - cos(th)) / (th * th);
            double wh[3][3] = {{0, -xi2, xi1}, {xi2, 0, -xi0}, {-xi1, xi0, 0}};
#pragma unroll
            for (int r = 0; r < 3; r++)
#pragma unroll
                for (int cc = 0; cc < 3; cc++) {
                    double w2 = 0;
#pragma unroll
                    for (int m = 0; m < 3; m++) w2 += wh[r][m] * wh[m][cc];
                    dR[r][cc] = (r == cc ? 1.0 : 0.0) + sA * wh[r][cc] + sB * w2;
                }
        }
        double R[3][3], t[3];
#pragma unroll
        for (int r = 0; r < 3; r++) {
#pragma unroll
            for (int cc = 0; cc < 3; cc++) R[r][cc] = pose[r * 4 + cc];
            t[r] = pose[r * 4 + 3];
        }
        double xt[3] = {xi3, xi4, xi5};
#pragma unroll
        for (int r = 0; r < 3; r++) {
#pragma unroll
            for (int cc = 0; cc < 3; cc++) {
                double s = 0;
#pragma unroll
                for (int m = 0; m < 3; m++) s += dR[r][m] * R[m][cc];
                pose[r * 4 + cc] = (float)s;
            }
            pose[r * 4 + 3] = (float)(dR[r][0] * t[0] + dR[r][1] * t[1] + dR[r][2] * t[2] + xt[r]);
        }
        for (int q = 0; q < 16; q++) pose_out[q] = pose[q];
    }
}

extern "C" void kernel_launch(void* const* d_in, const int* in_sizes, int n_in,
                              void* d_out, int out_size, void* d_ws, size_t ws_size,
                              hipStream_t stream) {
    const float* pose_in = (const float*)d_in[0];
    const float* depth0 = (const float*)d_in[1];
    const float* depth1 = (const float*)d_in[2];
    const float* K = (const float*)d_in[3];
    float* out = (float*)d_out;
    char* ws = (char*)d_ws;
    float* ws_pose = (float*)(ws + OFF_POSE);
    unsigned int* minmax = (unsigned int*)(ws + OFF_MINMAX);
    float* partials = (float*)(ws + OFF_PARTIALS);
    h4* nd16 = (h4*)(ws + OFF_ND16);

    k_init<<<1, 64, 0, stream>>>(pose_in, ws_pose, minmax);
    k_minmax<<<1024, 256, 0, stream>>>((const float4*)depth1, minmax);
    k_nm<<<RB, 256, 0, stream>>>(depth1, K, minmax, nd16);
    for (int it = 0; it < 3; ++it) {
        k_resid<<<RB, 256, 0, stream>>>((const float4*)depth0, K, nd16, ws_pose, partials);
        k_finish<<<1, 256, 0, stream>>>(partials, ws_pose, out);
    }
}

// Round 6
// 146.757 us; speedup vs baseline: 4.0852x; 2.2878x over previous
//
#include <hip/hip_runtime.h>
#include <math.h>

#define H_IMG 1080
#define W_IMG 1920
#define NPIX (H_IMG * W_IMG)
#define W4 480                                 // W_IMG / 4
#define QUADS (NPIX / 4)                       // 518400
#define RB 2025                                // QUADS / 256, exact
#define NACC 27

// ---- workspace layout (byte offsets) ----
#define OFF_POSE     0                         // 16 f32
#define OFF_MINMAX   64                        // 2 u32
#define OFF_SUMS     128                       // NACC f64 = 216 B
#define OFF_PARTIALS 512                       // NACC * RB f32 = 218700 B
#define OFF_ND16     219648                    // NPIX f16x4 (nx,ny,nz,d) = 16.6 MB

typedef _Float16 h4 __attribute__((ext_vector_type(4)));

__device__ __forceinline__ float clampf(float x, float lo, float hi) {
    return fminf(fmaxf(x, lo), hi);
}

__global__ void k_init(const float* __restrict__ pose_in, float* __restrict__ ws_pose,
                       unsigned int* __restrict__ minmax) {
    int t = threadIdx.x;
    if (t < 16) ws_pose[t] = pose_in[t];
    if (t == 16) { minmax[0] = 0x7F800000u; minmax[1] = 0u; }
}

__global__ void k_minmax(const float4* __restrict__ dq, unsigned int* __restrict__ minmax) {
    int tid = blockIdx.x * blockDim.x + threadIdx.x;
    int stride = gridDim.x * blockDim.x;
    float mn = INFINITY, mx = -INFINITY;
    for (int i = tid; i < QUADS; i += stride) {
        float4 v = dq[i];
        mn = fminf(mn, fminf(fminf(v.x, v.y), fminf(v.z, v.w)));
        mx = fmaxf(mx, fmaxf(fmaxf(v.x, v.y), fmaxf(v.z, v.w)));
    }
    for (int off = 32; off > 0; off >>= 1) {
        mn = fminf(mn, __shfl_down(mn, off));
        mx = fmaxf(mx, __shfl_down(mx, off));
    }
    __shared__ float smn[4], smx[4];
    int lane = threadIdx.x & 63, wid = threadIdx.x >> 6;
    if (lane == 0) { smn[wid] = mn; smx[wid] = mx; }
    __syncthreads();
    if (threadIdx.x == 0) {
        for (int w = 1; w < 4; w++) { mn = fminf(mn, smn[w]); mx = fmaxf(mx, smx[w]); }
        atomicMin(&minmax[0], __float_as_uint(mn));  // positive floats: bit order == value order
        atomicMax(&minmax[1], __float_as_uint(mx));
    }
}

// masked normals + depth packed to f16x4 (8 B/px). 4 consecutive pixels per thread.
__global__ __launch_bounds__(256)
void k_nm(const float* __restrict__ depth1, const float* __restrict__ Kmat,
          const unsigned int* __restrict__ minmax, h4* __restrict__ nd16) {
    int tid = threadIdx.x;
    int qid = blockIdx.x * 256 + tid;          // grid exactly RB*256 == QUADS
    float fx = Kmat[0], cx = Kmat[2], fy = Kmat[4], cy = Kmat[5];
    float ifx = 1.f / fx, ify = 1.f / fy;
    float dmin = __uint_as_float(minmax[0]), dmax = __uint_as_float(minmax[1]);
    int j = qid / W4;
    int i0 = (qid - j * W4) * 4;
    int r0 = j > 0 ? j - 1 : 0;
    int r2 = j < H_IMG - 1 ? j + 1 : H_IMG - 1;
    int il = i0 > 0 ? i0 - 1 : 0;
    int ir = i0 + 4 < W_IMG ? i0 + 4 : W_IMG - 1;
    const float* rp[3] = { depth1 + (size_t)r0 * W_IMG,
                           depth1 + (size_t)j  * W_IMG,
                           depth1 + (size_t)r2 * W_IMG };
    float d[3][6];
#pragma unroll
    for (int r = 0; r < 3; r++) {
        float4 m = *reinterpret_cast<const float4*>(rp[r] + i0);
        d[r][0] = rp[r][il]; d[r][1] = m.x; d[r][2] = m.y; d[r][3] = m.z; d[r][4] = m.w; d[r][5] = rp[r][ir];
    }
    float rowc[3] = { ((float)r0 - cy) * ify, ((float)j - cy) * ify, ((float)r2 - cy) * ify };
    float colc[6];
#pragma unroll
    for (int c = 0; c < 6; c++) {
        int col = i0 - 1 + c; col = col < 0 ? 0 : (col > W_IMG - 1 ? W_IMG - 1 : col);
        colc[c] = ((float)col - cx) * ifx;
    }
    float vx[3][6], vy[3][6];
#pragma unroll
    for (int r = 0; r < 3; r++)
#pragma unroll
        for (int c = 0; c < 6; c++) { vx[r][c] = colc[c] * d[r][c]; vy[r][c] = rowc[r] * d[r][c]; }
    h4 out[4];
#pragma unroll
    for (int p = 0; p < 4; p++) {
        int a = p, b = p + 1, e = p + 2;
        float dxx = -vx[0][a] + vx[0][e] - 2.f * vx[1][a] + 2.f * vx[1][e] - vx[2][a] + vx[2][e];
        float dxy = -vy[0][a] + vy[0][e] - 2.f * vy[1][a] + 2.f * vy[1][e] - vy[2][a] + vy[2][e];
        float dxz = -d[0][a] + d[0][e] - 2.f * d[1][a] + 2.f * d[1][e] - d[2][a] + d[2][e];
        float dyx = -vx[0][a] - 2.f * vx[0][b] - vx[0][e] + vx[2][a] + 2.f * vx[2][b] + vx[2][e];
        float dyy = -vy[0][a] - 2.f * vy[0][b] - vy[0][e] + vy[2][a] + 2.f * vy[2][b] + vy[2][e];
        float dyz = -d[0][a] - 2.f * d[0][b] - d[0][e] + d[2][a] + 2.f * d[2][b] + d[2][e];
        float nx = dxy * dyz - dxz * dyy;
        float ny = dxz * dyx - dxx * dyz;
        float nz = dxx * dyy - dxy * dyx;
        float inv = 1.f / (sqrtf(nx * nx + ny * ny + nz * nz) + 1e-8f);
        float dc = d[1][b];
        bool invalid = (dc <= dmin) || (dc >= dmax);   // exact f32 compare pre-pack
        float s = invalid ? 0.f : inv;
        out[p][0] = (_Float16)(nx * s);
        out[p][1] = (_Float16)(ny * s);
        out[p][2] = (_Float16)(nz * s);
        out[p][3] = (_Float16)dc;
    }
    h4* dst = nd16 + (size_t)j * W_IMG + i0;
#pragma unroll
    for (int p = 0; p < 4; p++) dst[p] = out[p];
}

// residual + Jacobian accumulation; all 16 gathers issued back-to-back (MLP).
__global__ __launch_bounds__(256)
void k_resid(const float4* __restrict__ depth0q, const float* __restrict__ Kmat,
             const h4* __restrict__ nd16, const float* __restrict__ pose,
             float* __restrict__ partials) {
    float fx = Kmat[0], cx = Kmat[2], fy = Kmat[4], cy = Kmat[5];
    float ifx = 1.f / fx, ify = 1.f / fy;
    float R00 = pose[0], R01 = pose[1], R02 = pose[2],  t0 = pose[3];
    float R10 = pose[4], R11 = pose[5], R12 = pose[6],  t1 = pose[7];
    float R20 = pose[8], R21 = pose[9], R22 = pose[10], t2 = pose[11];

    float acc[NACC];
#pragma unroll
    for (int k = 0; k < NACC; k++) acc[k] = 0.f;

    int tid = threadIdx.x;
    int qid = blockIdx.x * 256 + tid;          // grid exactly RB*256 == QUADS
    int j = qid / W4;
    int i0 = (qid - j * W4) * 4;
    float jf = (float)j;
    float4 d4 = depth0q[qid];
    float d0s[4] = {d4.x, d4.y, d4.z, d4.w};

    float px[4], py[4], pz[4], wx[4], wy[4];
    int x0[4], y0[4], y1v[4];
    bool inview[4];
#pragma unroll
    for (int p = 0; p < 4; p++) {
        float d0 = d0s[p];
        float v0x = ((float)(i0 + p) - cx) * ifx * d0;
        float v0y = (jf - cy) * ify * d0;
        float X = R00 * v0x + R01 * v0y + R02 * d0 + t0;
        float Y = R10 * v0x + R11 * v0y + R12 * d0 + t1;
        float Z = R20 * v0x + R21 * v0y + R22 * d0 + t2;
        float u, v; bool iv;
        if (Z > 1e-6f) {
            float rz = 1.f / Z;
            u = X * rz * fx + cx;
            v = Y * rz * fy + cy;
            iv = (u > 0.f) && (u < (float)(W_IMG - 1)) && (v > 0.f) && (v < (float)(H_IMG - 1));
        } else { u = 0.f; v = 0.f; iv = false; }
        float uc = clampf(u, 0.f, (float)(W_IMG - 1));
        float vc = clampf(v, 0.f, (float)(H_IMG - 1));
        float x0f = floorf(uc), y0f = floorf(vc);
        x0[p] = (int)x0f; y0[p] = (int)y0f;
        y1v[p] = min(y0[p] + 1, H_IMG - 1);
        wx[p] = uc - x0f; wy[p] = vc - y0f;
        px[p] = X; py[p] = Y; pz[p] = Z; inview[p] = iv;
    }
    // 16 gathers of 8 B, all independent; x-corners adjacent (x1==x0+1 whenever inview).
    h4 a0[4], a1[4], b0[4], b1[4];
#pragma unroll
    for (int p = 0; p < 4; p++) {
        int base0 = y0[p] * W_IMG + x0[p];
        int base1 = y1v[p] * W_IMG + x0[p];
        a0[p] = nd16[base0]; a1[p] = nd16[base0 + 1];
        b0[p] = nd16[base1]; b1[p] = nd16[base1 + 1];
    }
#pragma unroll
    for (int p = 0; p < 4; p++) {
        float w1x = 1.f - wx[p], w1y = 1.f - wy[p];
        float d00 = (float)a0[p][3], d01 = (float)a1[p][3];
        float d10 = (float)b0[p][3], d11 = (float)b1[p][3];
        float cX0 = ((float)x0[p] - cx) * ifx, cX1 = ((float)(x0[p] + 1) - cx) * ifx;
        float cY0 = ((float)y0[p] - cy) * ify, cY1 = ((float)y1v[p] - cy) * ify;
        float rvx = (cX0 * d00 * w1x + cX1 * d01 * wx[p]) * w1y + (cX0 * d10 * w1x + cX1 * d11 * wx[p]) * wy[p];
        float rvy = (cY0 * d00 * w1x + cY0 * d01 * wx[p]) * w1y + (cY1 * d10 * w1x + cY1 * d11 * wx[p]) * wy[p];
        float rvz = (d00 * w1x + d01 * wx[p]) * w1y + (d10 * w1x + d11 * wx[p]) * wy[p];
        float rnx = ((float)a0[p][0] * w1x + (float)a1[p][0] * wx[p]) * w1y
                  + ((float)b0[p][0] * w1x + (float)b1[p][0] * wx[p]) * wy[p];
        float rny = ((float)a0[p][1] * w1x + (float)a1[p][1] * wx[p]) * w1y
                  + ((float)b0[p][1] * w1x + (float)b1[p][1] * wx[p]) * wy[p];
        float rnz = ((float)a0[p][2] * w1x + (float)a1[p][2] * wx[p]) * w1y
                  + ((float)b0[p][2] * w1x + (float)b1[p][2] * wx[p]) * wy[p];
        bool mask1 = rvz > 0.f;
        float ddx = px[p] - rvx, ddy = py[p] - rvy, ddz = pz[p] - rvz;
        bool occ = (!inview[p]) || (sqrtf(ddx * ddx + ddy * ddy + ddz * ddz) > 0.1f);
        bool bad = occ || !(d0s[p] > 0.f) || (!mask1);
        if (!bad) {
            float res = rnx * ddx + rny * ddy + rnz * ddz;
            float jv[6];
            jv[0] = -(py[p] * rnz - pz[p] * rny);
            jv[1] = -(pz[p] * rnx - px[p] * rnz);
            jv[2] = -(px[p] * rny - py[p] * rnx);
            jv[3] = -rnx; jv[4] = -rny; jv[5] = -rnz;
            int k = 0;
#pragma unroll
            for (int a = 0; a < 6; a++)
#pragma unroll
                for (int b = a; b < 6; b++) { acc[k] += jv[a] * jv[b]; k++; }
#pragma unroll
            for (int a = 0; a < 6; a++) acc[21 + a] += jv[a] * res;
        }
    }

    // block reduction: 2x shfl_xor pre-reduce (4 lanes) -> LDS [27][64] -> [27][8] -> f32 partial
    __shared__ float red[NACC][64];
    __shared__ float part2[NACC][8];
#pragma unroll
    for (int k = 0; k < NACC; k++) {
        float v = acc[k];
        v += __shfl_xor(v, 1);
        v += __shfl_xor(v, 2);
        if ((tid & 3) == 0) red[k][tid >> 2] = v;
    }
    __syncthreads();
    if (tid < NACC * 8) {
        int k = tid >> 3, seg = tid & 7;
        const float4* row = reinterpret_cast<const float4*>(&red[k][seg * 8]);
        float4 a = row[0], b = row[1];
        part2[k][seg] = (a.x + a.y + a.z + a.w) + (b.x + b.y + b.z + b.w);
    }
    __syncthreads();
    if (tid < NACC) {
        float s = 0.f;
#pragma unroll
        for (int m = 0; m < 8; m++) s += part2[tid][m];
        partials[(size_t)tid * RB + blockIdx.x] = s;
    }
}

// one block per accumulator k: coalesced parallel reduction of RB f32 partials in f64
__global__ void k_reduce(const float* __restrict__ partials, double* __restrict__ sums) {
    int k = blockIdx.x;
    double v = 0.0;
    for (int i = threadIdx.x; i < RB; i += 256) v += (double)partials[(size_t)k * RB + i];
    for (int off = 32; off > 0; off >>= 1) v += __shfl_down(v, off);
    __shared__ double sw[4];
    int lane = threadIdx.x & 63, wid = threadIdx.x >> 6;
    if (lane == 0) sw[wid] = v;
    __syncthreads();
    if (threadIdx.x == 0) sums[k] = sw[0] + sw[1] + sw[2] + sw[3];
}

// single block: 27 scalar loads, 6x6 GN solve, update pose, write out.
__global__ void k_solve(const double* __restrict__ sums, float* __restrict__ pose,
                        float* __restrict__ pose_out) {
    __shared__ double ssum[NACC];
    int tid = threadIdx.x;
    if (tid < NACC) ssum[tid] = sums[tid];
    __syncthreads();
    if (tid == 0) {
        double sM[6][7];
        int k = 0;
        for (int a = 0; a < 6; a++)
            for (int c = a; c < 6; c++) {
                double s = ssum[k++];
                sM[a][c] = s; sM[c][a] = s;
            }
        double tr = sM[0][0] + sM[1][1] + sM[2][2] + sM[3][3] + sM[4][4] + sM[5][5];
        for (int a = 0; a < 6; a++) sM[a][a] += tr * 0.001;
        for (int a = 0; a < 6; a++) sM[a][6] = ssum[21 + a];
        for (int c = 0; c < 6; c++) {
            int piv = c;
            double best = fabs(sM[c][c]);
            for (int r = c + 1; r < 6; r++) {
                double v = fabs(sM[r][c]);
                if (v > best) { best = v; piv = r; }
            }
            if (piv != c)
                for (int q = c; q < 7; q++) { double t = sM[c][q]; sM[c][q] = sM[piv][q]; sM[piv][q] = t; }
            double pv = sM[c][c];
            for (int r = 0; r < 6; r++) {
                if (r == c) continue;
                double f = sM[r][c] / pv;
                for (int q = c; q < 7; q++) sM[r][q] -= f * sM[c][q];
            }
        }
        double xi0 = sM[0][6] / sM[0][0], xi1 = sM[1][6] / sM[1][1], xi2 = sM[2][6] / sM[2][2];
        double xi3 = sM[3][6] / sM[3][3], xi4 = sM[4][6] / sM[4][4], xi5 = sM[5][6] / sM[5][5];
        double th = sqrt(xi0 * xi0 + xi1 * xi1 + xi2 * xi2);
        double dR[3][3] = {{1, 0, 0}, {0, 1, 0}, {0, 0, 1}};
        if (th > 1e-10) {
            double sA = sin(th) / th;
            double sB = (1.0 - cos(th)) / (th * th);
            double wh[3][3] = {{0, -xi2, xi1}, {xi2, 0, -xi0}, {-xi1, xi0, 0}};
#pragma unroll
            for (int r = 0; r < 3; r++)
#pragma unroll
                for (int cc = 0; cc < 3; cc++) {
                    double w2 = 0;
#pragma unroll
                    for (int m = 0; m < 3; m++) w2 += wh[r][m] * wh[m][cc];
                    dR[r][cc] = (r == cc ? 1.0 : 0.0) + sA * wh[r][cc] + sB * w2;
                }
        }
        double R[3][3], t[3];
#pragma unroll
        for (int r = 0; r < 3; r++) {
#pragma unroll
            for (int cc = 0; cc < 3; cc++) R[r][cc] = pose[r * 4 + cc];
            t[r] = pose[r * 4 + 3];
        }
        double xt[3] = {xi3, xi4, xi5};
#pragma unroll
        for (int r = 0; r < 3; r++) {
#pragma unroll
            for (int cc = 0; cc < 3; cc++) {
                double s = 0;
#pragma unroll
                for (int m = 0; m < 3; m++) s += dR[r][m] * R[m][cc];
                pose[r * 4 + cc] = (float)s;
            }
            pose[r * 4 + 3] = (float)(dR[r][0] * t[0] + dR[r][1] * t[1] + dR[r][2] * t[2] + xt[r]);
        }
        for (int q = 0; q < 16; q++) pose_out[q] = pose[q];
    }
}

extern "C" void kernel_launch(void* const* d_in, const int* in_sizes, int n_in,
                              void* d_out, int out_size, void* d_ws, size_t ws_size,
                              hipStream_t stream) {
    const float* pose_in = (const float*)d_in[0];
    const float* depth0 = (const float*)d_in[1];
    const float* depth1 = (const float*)d_in[2];
    const float* K = (const float*)d_in[3];
    float* out = (float*)d_out;
    char* ws = (char*)d_ws;
    float* ws_pose = (float*)(ws + OFF_POSE);
    unsigned int* minmax = (unsigned int*)(ws + OFF_MINMAX);
    double* sums = (double*)(ws + OFF_SUMS);
    float* partials = (float*)(ws + OFF_PARTIALS);
    h4* nd16 = (h4*)(ws + OFF_ND16);

    k_init<<<1, 64, 0, stream>>>(pose_in, ws_pose, minmax);
    k_minmax<<<1024, 256, 0, stream>>>((const float4*)depth1, minmax);
    k_nm<<<RB, 256, 0, stream>>>(depth1, K, minmax, nd16);
    for (int it = 0; it < 3; ++it) {
        k_resid<<<RB, 256, 0, stream>>>((const float4*)depth0, K, nd16, ws_pose, partials);
        k_reduce<<<NACC, 256, 0, stream>>>(partials, sums);
        k_solve<<<1, 64, 0, stream>>>(sums, ws_pose, out);
    }
}

// Round 7
// 146.280 us; speedup vs baseline: 4.0986x; 1.0033x over previous
//
#include <hip/hip_runtime.h>
#include <math.h>

#define H_IMG 1080
#define W_IMG 1920
#define NPIX (H_IMG * W_IMG)
#define W4 480                                 // W_IMG / 4
#define QUADS (NPIX / 4)                       // 518400
#define RB 2025                                // QUADS / 256, exact
#define NACC 27

// ---- workspace layout (byte offsets) ----
#define OFF_POSE     0                         // 16 f32
#define OFF_MINMAX   64                        // 2 u32
#define OFF_COUNT    128                       // 1 u32 ticket
#define OFF_SUMS     192                       // NACC f64 = 216 B
#define OFF_PARTIALS 512                       // NACC * RB f32 = 218700 B
#define OFF_ND16     219648                    // NPIX f16x4 (nx,ny,nz,d) = 16.6 MB

typedef _Float16 h4 __attribute__((ext_vector_type(4)));

__device__ __forceinline__ float clampf(float x, float lo, float hi) {
    return fminf(fmaxf(x, lo), hi);
}

__global__ void k_init(const float* __restrict__ pose_in, float* __restrict__ ws_pose,
                       unsigned int* __restrict__ minmax, unsigned int* __restrict__ counter) {
    int t = threadIdx.x;
    if (t < 16) ws_pose[t] = pose_in[t];
    if (t == 16) { minmax[0] = 0x7F800000u; minmax[1] = 0u; }
    if (t == 17) *counter = 0u;
}

__global__ void k_minmax(const float4* __restrict__ dq, unsigned int* __restrict__ minmax) {
    int tid = blockIdx.x * blockDim.x + threadIdx.x;
    int stride = gridDim.x * blockDim.x;
    float mn = INFINITY, mx = -INFINITY;
    for (int i = tid; i < QUADS; i += stride) {
        float4 v = dq[i];
        mn = fminf(mn, fminf(fminf(v.x, v.y), fminf(v.z, v.w)));
        mx = fmaxf(mx, fmaxf(fmaxf(v.x, v.y), fmaxf(v.z, v.w)));
    }
    for (int off = 32; off > 0; off >>= 1) {
        mn = fminf(mn, __shfl_down(mn, off));
        mx = fmaxf(mx, __shfl_down(mx, off));
    }
    __shared__ float smn[4], smx[4];
    int lane = threadIdx.x & 63, wid = threadIdx.x >> 6;
    if (lane == 0) { smn[wid] = mn; smx[wid] = mx; }
    __syncthreads();
    if (threadIdx.x == 0) {
        for (int w = 1; w < 4; w++) { mn = fminf(mn, smn[w]); mx = fmaxf(mx, smx[w]); }
        atomicMin(&minmax[0], __float_as_uint(mn));  // positive floats: bit order == value order
        atomicMax(&minmax[1], __float_as_uint(mx));
    }
}

// masked normals + depth packed to f16x4 (8 B/px). 4 consecutive pixels per thread.
__global__ __launch_bounds__(256)
void k_nm(const float* __restrict__ depth1, const float* __restrict__ Kmat,
          const unsigned int* __restrict__ minmax, h4* __restrict__ nd16) {
    int tid = threadIdx.x;
    int qid = blockIdx.x * 256 + tid;          // grid exactly RB*256 == QUADS
    float fx = Kmat[0], cx = Kmat[2], fy = Kmat[4], cy = Kmat[5];
    float ifx = 1.f / fx, ify = 1.f / fy;
    float dmin = __uint_as_float(minmax[0]), dmax = __uint_as_float(minmax[1]);
    int j = qid / W4;
    int i0 = (qid - j * W4) * 4;
    int r0 = j > 0 ? j - 1 : 0;
    int r2 = j < H_IMG - 1 ? j + 1 : H_IMG - 1;
    int il = i0 > 0 ? i0 - 1 : 0;
    int ir = i0 + 4 < W_IMG ? i0 + 4 : W_IMG - 1;
    const float* rp[3] = { depth1 + (size_t)r0 * W_IMG,
                           depth1 + (size_t)j  * W_IMG,
                           depth1 + (size_t)r2 * W_IMG };
    float d[3][6];
#pragma unroll
    for (int r = 0; r < 3; r++) {
        float4 m = *reinterpret_cast<const float4*>(rp[r] + i0);
        d[r][0] = rp[r][il]; d[r][1] = m.x; d[r][2] = m.y; d[r][3] = m.z; d[r][4] = m.w; d[r][5] = rp[r][ir];
    }
    float rowc[3] = { ((float)r0 - cy) * ify, ((float)j - cy) * ify, ((float)r2 - cy) * ify };
    float colc[6];
#pragma unroll
    for (int c = 0; c < 6; c++) {
        int col = i0 - 1 + c; col = col < 0 ? 0 : (col > W_IMG - 1 ? W_IMG - 1 : col);
        colc[c] = ((float)col - cx) * ifx;
    }
    float vx[3][6], vy[3][6];
#pragma unroll
    for (int r = 0; r < 3; r++)
#pragma unroll
        for (int c = 0; c < 6; c++) { vx[r][c] = colc[c] * d[r][c]; vy[r][c] = rowc[r] * d[r][c]; }
    h4 out[4];
#pragma unroll
    for (int p = 0; p < 4; p++) {
        int a = p, b = p + 1, e = p + 2;
        float dxx = -vx[0][a] + vx[0][e] - 2.f * vx[1][a] + 2.f * vx[1][e] - vx[2][a] + vx[2][e];
        float dxy = -vy[0][a] + vy[0][e] - 2.f * vy[1][a] + 2.f * vy[1][e] - vy[2][a] + vy[2][e];
        float dxz = -d[0][a] + d[0][e] - 2.f * d[1][a] + 2.f * d[1][e] - d[2][a] + d[2][e];
        float dyx = -vx[0][a] - 2.f * vx[0][b] - vx[0][e] + vx[2][a] + 2.f * vx[2][b] + vx[2][e];
        float dyy = -vy[0][a] - 2.f * vy[0][b] - vy[0][e] + vy[2][a] + 2.f * vy[2][b] + vy[2][e];
        float dyz = -d[0][a] - 2.f * d[0][b] - d[0][e] + d[2][a] + 2.f * d[2][b] + d[2][e];
        float nx = dxy * dyz - dxz * dyy;
        float ny = dxz * dyx - dxx * dyz;
        float nz = dxx * dyy - dxy * dyx;
        float inv = 1.f / (sqrtf(nx * nx + ny * ny + nz * nz) + 1e-8f);
        float dc = d[1][b];
        bool invalid = (dc <= dmin) || (dc >= dmax);   // exact f32 compare pre-pack
        float s = invalid ? 0.f : inv;
        out[p][0] = (_Float16)(nx * s);
        out[p][1] = (_Float16)(ny * s);
        out[p][2] = (_Float16)(nz * s);
        out[p][3] = (_Float16)dc;
    }
    h4* dst = nd16 + (size_t)j * W_IMG + i0;
#pragma unroll
    for (int p = 0; p < 4; p++) dst[p] = out[p];
}

// residual + Jacobian. STRIDED pixel->lane map: thread tid handles pixels
// base + p*256 + tid, so adjacent lanes gather adjacent pixels (8 B stride)
// -> ~4-8 cache lines per gather instruction instead of 32.
__global__ __launch_bounds__(256)
void k_resid(const float* __restrict__ depth0, const float* __restrict__ Kmat,
             const h4* __restrict__ nd16, const float* __restrict__ pose,
             float* __restrict__ partials) {
    float fx = Kmat[0], cx = Kmat[2], fy = Kmat[4], cy = Kmat[5];
    float ifx = 1.f / fx, ify = 1.f / fy;
    float R00 = pose[0], R01 = pose[1], R02 = pose[2],  t0 = pose[3];
    float R10 = pose[4], R11 = pose[5], R12 = pose[6],  t1 = pose[7];
    float R20 = pose[8], R21 = pose[9], R22 = pose[10], t2 = pose[11];

    float acc[NACC];
#pragma unroll
    for (int k = 0; k < NACC; k++) acc[k] = 0.f;

    int tid = threadIdx.x;
    int base = blockIdx.x * 1024;              // grid*1024 == NPIX exactly

    float d0s[4];
#pragma unroll
    for (int p = 0; p < 4; p++) d0s[p] = depth0[base + p * 256 + tid];  // 4 coalesced loads

    float px[4], py[4], pz[4], wx[4], wy[4];
    int x0[4], y0[4], y1v[4];
    bool inview[4];
#pragma unroll
    for (int p = 0; p < 4; p++) {
        int idx = base + p * 256 + tid;
        int j = idx / W_IMG;
        int i = idx - j * W_IMG;
        float d0 = d0s[p];
        float v0x = ((float)i - cx) * ifx * d0;
        float v0y = ((float)j - cy) * ify * d0;
        float X = R00 * v0x + R01 * v0y + R02 * d0 + t0;
        float Y = R10 * v0x + R11 * v0y + R12 * d0 + t1;
        float Z = R20 * v0x + R21 * v0y + R22 * d0 + t2;
        float u, v; bool iv;
        if (Z > 1e-6f) {
            float rz = 1.f / Z;
            u = X * rz * fx + cx;
            v = Y * rz * fy + cy;
            iv = (u > 0.f) && (u < (float)(W_IMG - 1)) && (v > 0.f) && (v < (float)(H_IMG - 1));
        } else { u = 0.f; v = 0.f; iv = false; }
        float uc = clampf(u, 0.f, (float)(W_IMG - 1));
        float vc = clampf(v, 0.f, (float)(H_IMG - 1));
        float x0f = floorf(uc), y0f = floorf(vc);
        x0[p] = (int)x0f; y0[p] = (int)y0f;
        y1v[p] = min(y0[p] + 1, H_IMG - 1);
        wx[p] = uc - x0f; wy[p] = vc - y0f;
        px[p] = X; py[p] = Y; pz[p] = Z; inview[p] = iv;
    }
    // 16 gathers of 8 B, all independent; x-corners adjacent (x1==x0+1 whenever inview).
    h4 a0[4], a1[4], b0[4], b1[4];
#pragma unroll
    for (int p = 0; p < 4; p++) {
        int base0 = y0[p] * W_IMG + x0[p];
        int base1 = y1v[p] * W_IMG + x0[p];
        a0[p] = nd16[base0]; a1[p] = nd16[base0 + 1];
        b0[p] = nd16[base1]; b1[p] = nd16[base1 + 1];
    }
#pragma unroll
    for (int p = 0; p < 4; p++) {
        float w1x = 1.f - wx[p], w1y = 1.f - wy[p];
        float d00 = (float)a0[p][3], d01 = (float)a1[p][3];
        float d10 = (float)b0[p][3], d11 = (float)b1[p][3];
        float cX0 = ((float)x0[p] - cx) * ifx, cX1 = ((float)(x0[p] + 1) - cx) * ifx;
        float cY0 = ((float)y0[p] - cy) * ify, cY1 = ((float)y1v[p] - cy) * ify;
        float rvx = (cX0 * d00 * w1x + cX1 * d01 * wx[p]) * w1y + (cX0 * d10 * w1x + cX1 * d11 * wx[p]) * wy[p];
        float rvy = (cY0 * d00 * w1x + cY0 * d01 * wx[p]) * w1y + (cY1 * d10 * w1x + cY1 * d11 * wx[p]) * wy[p];
        float rvz = (d00 * w1x + d01 * wx[p]) * w1y + (d10 * w1x + d11 * wx[p]) * wy[p];
        float rnx = ((float)a0[p][0] * w1x + (float)a1[p][0] * wx[p]) * w1y
                  + ((float)b0[p][0] * w1x + (float)b1[p][0] * wx[p]) * wy[p];
        float rny = ((float)a0[p][1] * w1x + (float)a1[p][1] * wx[p]) * w1y
                  + ((float)b0[p][1] * w1x + (float)b1[p][1] * wx[p]) * wy[p];
        float rnz = ((float)a0[p][2] * w1x + (float)a1[p][2] * wx[p]) * w1y
                  + ((float)b0[p][2] * w1x + (float)b1[p][2] * wx[p]) * wy[p];
        bool mask1 = rvz > 0.f;
        float ddx = px[p] - rvx, ddy = py[p] - rvy, ddz = pz[p] - rvz;
        bool occ = (!inview[p]) || (sqrtf(ddx * ddx + ddy * ddy + ddz * ddz) > 0.1f);
        bool bad = occ || !(d0s[p] > 0.f) || (!mask1);
        if (!bad) {
            float res = rnx * ddx + rny * ddy + rnz * ddz;
            float jv[6];
            jv[0] = -(py[p] * rnz - pz[p] * rny);
            jv[1] = -(pz[p] * rnx - px[p] * rnz);
            jv[2] = -(px[p] * rny - py[p] * rnx);
            jv[3] = -rnx; jv[4] = -rny; jv[5] = -rnz;
            int k = 0;
#pragma unroll
            for (int a = 0; a < 6; a++)
#pragma unroll
                for (int b = a; b < 6; b++) { acc[k] += jv[a] * jv[b]; k++; }
#pragma unroll
            for (int a = 0; a < 6; a++) acc[21 + a] += jv[a] * res;
        }
    }

    // block reduction: 2x shfl_xor pre-reduce (4 lanes) -> LDS [27][64] -> [27][8] -> f32 partial
    __shared__ float red[NACC][64];
    __shared__ float part2[NACC][8];
#pragma unroll
    for (int k = 0; k < NACC; k++) {
        float v = acc[k];
        v += __shfl_xor(v, 1);
        v += __shfl_xor(v, 2);
        if ((tid & 3) == 0) red[k][tid >> 2] = v;
    }
    __syncthreads();
    if (tid < NACC * 8) {
        int k = tid >> 3, seg = tid & 7;
        const float4* row = reinterpret_cast<const float4*>(&red[k][seg * 8]);
        float4 a = row[0], b = row[1];
        part2[k][seg] = (a.x + a.y + a.z + a.w) + (b.x + b.y + b.z + b.w);
    }
    __syncthreads();
    if (tid < NACC) {
        float s = 0.f;
#pragma unroll
        for (int m = 0; m < 8; m++) s += part2[tid][m];
        partials[(size_t)tid * RB + blockIdx.x] = s;
    }
}

// 27 blocks: block k reduces RB f32 partials (f64); last block done runs the
// 6x6 GN solve. 27 device fences are cheap (round-4's failure was 2025).
__global__ __launch_bounds__(256)
void k_reduce_solve(const float* __restrict__ partials, double* __restrict__ sums,
                    unsigned int* __restrict__ counter, float* __restrict__ pose,
                    float* __restrict__ pose_out) {
    int k = blockIdx.x;
    int tid = threadIdx.x;
    double v = 0.0;
    for (int i = tid; i < RB; i += 256) v += (double)partials[(size_t)k * RB + i];
    for (int off = 32; off > 0; off >>= 1) v += __shfl_down(v, off);
    __shared__ double sw[4];
    __shared__ int amLast;
    int lane = tid & 63, wid = tid >> 6;
    if (lane == 0) sw[wid] = v;
    __syncthreads();
    if (tid == 0) {
        sums[k] = sw[0] + sw[1] + sw[2] + sw[3];
        __threadfence();
        unsigned int old = atomicAdd(counter, 1u);
        amLast = (old == NACC - 1) ? 1 : 0;
    }
    __syncthreads();
    if (!amLast) return;
    __threadfence();

    if (tid == 0) {
        double ssum[NACC];
        for (int q = 0; q < NACC; q++) ssum[q] = sums[q];
        double sM[6][7];
        int kk = 0;
        for (int a = 0; a < 6; a++)
            for (int c = a; c < 6; c++) {
                double s = ssum[kk++];
                sM[a][c] = s; sM[c][a] = s;
            }
        double tr = sM[0][0] + sM[1][1] + sM[2][2] + sM[3][3] + sM[4][4] + sM[5][5];
        for (int a = 0; a < 6; a++) sM[a][a] += tr * 0.001;
        for (int a = 0; a < 6; a++) sM[a][6] = ssum[21 + a];
        for (int c = 0; c < 6; c++) {
            int piv = c;
            double best = fabs(sM[c][c]);
            for (int r = c + 1; r < 6; r++) {
                double vv = fabs(sM[r][c]);
                if (vv > best) { best = vv; piv = r; }
            }
            if (piv != c)
                for (int q = c; q < 7; q++) { double t = sM[c][q]; sM[c][q] = sM[piv][q]; sM[piv][q] = t; }
            double pv = sM[c][c];
            for (int r = 0; r < 6; r++) {
                if (r == c) continue;
                double f = sM[r][c] / pv;
                for (int q = c; q < 7; q++) sM[r][q] -= f * sM[c][q];
            }
        }
        double xi0 = sM[0][6] / sM[0][0], xi1 = sM[1][6] / sM[1][1], xi2 = sM[2][6] / sM[2][2];
        double xi3 = sM[3][6] / sM[3][3], xi4 = sM[4][6] / sM[4][4], xi5 = sM[5][6] / sM[5][5];
        double th = sqrt(xi0 * xi0 + xi1 * xi1 + xi2 * xi2);
        double dR[3][3] = {{1, 0, 0}, {0, 1, 0}, {0, 0, 1}};
        if (th > 1e-10) {
            double sA = sin(th) / th;
            double sB = (1.0 - cos(th)) / (th * th);
            double wh[3][3] = {{0, -xi2, xi1}, {xi2, 0, -xi0}, {-xi1, xi0, 0}};
#pragma unroll
            for (int r = 0; r < 3; r++)
#pragma unroll
                for (int cc = 0; cc < 3; cc++) {
                    double w2 = 0;
#pragma unroll
                    for (int m = 0; m < 3; m++) w2 += wh[r][m] * wh[m][cc];
                    dR[r][cc] = (r == cc ? 1.0 : 0.0) + sA * wh[r][cc] + sB * w2;
                }
        }
        double R[3][3], t[3];
#pragma unroll
        for (int r = 0; r < 3; r++) {
#pragma unroll
            for (int cc = 0; cc < 3; cc++) R[r][cc] = pose[r * 4 + cc];
            t[r] = pose[r * 4 + 3];
        }
        double xt[3] = {xi3, xi4, xi5};
#pragma unroll
        for (int r = 0; r < 3; r++) {
#pragma unroll
            for (int cc = 0; cc < 3; cc++) {
                double s = 0;
#pragma unroll
                for (int m = 0; m < 3; m++) s += dR[r][m] * R[m][cc];
                pose[r * 4 + cc] = (float)s;
            }
            pose[r * 4 + 3] = (float)(dR[r][0] * t[0] + dR[r][1] * t[1] + dR[r][2] * t[2] + xt[r]);
        }
        *counter = 0u;                         // re-arm for next dispatch / replay
        for (int q = 0; q < 16; q++) pose_out[q] = pose[q];
    }
}

extern "C" void kernel_launch(void* const* d_in, const int* in_sizes, int n_in,
                              void* d_out, int out_size, void* d_ws, size_t ws_size,
                              hipStream_t stream) {
    const float* pose_in = (const float*)d_in[0];
    const float* depth0 = (const float*)d_in[1];
    const float* depth1 = (const float*)d_in[2];
    const float* K = (const float*)d_in[3];
    float* out = (float*)d_out;
    char* ws = (char*)d_ws;
    float* ws_pose = (float*)(ws + OFF_POSE);
    unsigned int* minmax = (unsigned int*)(ws + OFF_MINMAX);
    unsigned int* counter = (unsigned int*)(ws + OFF_COUNT);
    double* sums = (double*)(ws + OFF_SUMS);
    float* partials = (float*)(ws + OFF_PARTIALS);
    h4* nd16 = (h4*)(ws + OFF_ND16);

    k_init<<<1, 64, 0, stream>>>(pose_in, ws_pose, minmax, counter);
    k_minmax<<<1024, 256, 0, stream>>>((const float4*)depth1, minmax);
    k_nm<<<RB, 256, 0, stream>>>(depth1, K, minmax, nd16);
    for (int it = 0; it < 3; ++it) {
        k_resid<<<RB, 256, 0, stream>>>(depth0, K, nd16, ws_pose, partials);
        k_reduce_solve<<<NACC, 256, 0, stream>>>(partials, sums, counter, ws_pose, out);
    }
}